// Round 6
// baseline (1301.463 us; speedup 1.0000x reference)
//
#include <hip/hip_runtime.h>
#include <hip/hip_bf16.h>

#define N_NODES 100000
#define NB 784   // buckets of 128 nodes: 784*128 = 100352 >= N_NODES
#define NPAD 100352
#define BSH 7
#define BMASK 127

// ---------------------------------------------------------------------------
// Fused dual-GEMM, layer 1:
//   h[r][c] = relu( mean1[r]@W1n[:,c] + x[r]@W1s[:,c] + b1[c] )
// Thread tile 4 rows x 4 cols: A-values register-reused across 4 cols
// (global load instrs /16 vs 1-col threads), W read as float4 from LDS.
// Block tile: 64 rows. FMA:mem-instr ratio 8:1 -> compute-issue bound.
// ---------------------------------------------------------------------------
__global__ __launch_bounds__(256) void gemm1_k(
    const float* __restrict__ mean1, const float* __restrict__ x,
    const float* __restrict__ W1n, const float* __restrict__ W1s,
    const float* __restrict__ b1, float* __restrict__ h, int M) {
  __shared__ float Wn[64 * 64];
  __shared__ float Ws[64 * 64];
  const int tid = threadIdx.x;
  for (int i = tid; i < 1024; i += 256) {
    ((float4*)Wn)[i] = ((const float4*)W1n)[i];
    ((float4*)Ws)[i] = ((const float4*)W1s)[i];
  }
  __syncthreads();

  const int tx = tid & 15;  // cols 4tx..4tx+3
  const int ty = tid >> 4;  // rows 4ty..4ty+3 within 64-row block tile
  const int row_base = blockIdx.x * 64 + ty * 4;

  // Clamp load rows (safe reads); stores predicated on real row < M.
  long long rr[4];
#pragma unroll
  for (int r = 0; r < 4; ++r) {
    int rowr = row_base + r;
    rr[r] = rowr < M ? rowr : (M - 1);
  }
  const float4* mp[4];
  const float4* xp[4];
#pragma unroll
  for (int r = 0; r < 4; ++r) {
    mp[r] = (const float4*)(mean1 + rr[r] * 64);
    xp[r] = (const float4*)(x + rr[r] * 64);
  }

  float4 acc[4];
#pragma unroll
  for (int r = 0; r < 4; ++r) acc[r] = make_float4(0.f, 0.f, 0.f, 0.f);

#pragma unroll
  for (int k4 = 0; k4 < 16; ++k4) {
    float4 mv[4], xv[4];
#pragma unroll
    for (int r = 0; r < 4; ++r) {
      mv[r] = mp[r][k4];
      xv[r] = xp[r][k4];
    }
    float4 wn[4], ws[4];
#pragma unroll
    for (int kk = 0; kk < 4; ++kk) {
      wn[kk] = *(const float4*)&Wn[(4 * k4 + kk) * 64 + 4 * tx];
      ws[kk] = *(const float4*)&Ws[(4 * k4 + kk) * 64 + 4 * tx];
    }
#pragma unroll
    for (int r = 0; r < 4; ++r) {
      acc[r].x = fmaf(mv[r].x, wn[0].x, acc[r].x);
      acc[r].y = fmaf(mv[r].x, wn[0].y, acc[r].y);
      acc[r].z = fmaf(mv[r].x, wn[0].z, acc[r].z);
      acc[r].w = fmaf(mv[r].x, wn[0].w, acc[r].w);
      acc[r].x = fmaf(mv[r].y, wn[1].x, acc[r].x);
      acc[r].y = fmaf(mv[r].y, wn[1].y, acc[r].y);
      acc[r].z = fmaf(mv[r].y, wn[1].z, acc[r].z);
      acc[r].w = fmaf(mv[r].y, wn[1].w, acc[r].w);
      acc[r].x = fmaf(mv[r].z, wn[2].x, acc[r].x);
      acc[r].y = fmaf(mv[r].z, wn[2].y, acc[r].y);
      acc[r].z = fmaf(mv[r].z, wn[2].z, acc[r].z);
      acc[r].w = fmaf(mv[r].z, wn[2].w, acc[r].w);
      acc[r].x = fmaf(mv[r].w, wn[3].x, acc[r].x);
      acc[r].y = fmaf(mv[r].w, wn[3].y, acc[r].y);
      acc[r].z = fmaf(mv[r].w, wn[3].z, acc[r].z);
      acc[r].w = fmaf(mv[r].w, wn[3].w, acc[r].w);
      acc[r].x = fmaf(xv[r].x, ws[0].x, acc[r].x);
      acc[r].y = fmaf(xv[r].x, ws[0].y, acc[r].y);
      acc[r].z = fmaf(xv[r].x, ws[0].z, acc[r].z);
      acc[r].w = fmaf(xv[r].x, ws[0].w, acc[r].w);
      acc[r].x = fmaf(xv[r].y, ws[1].x, acc[r].x);
      acc[r].y = fmaf(xv[r].y, ws[1].y, acc[r].y);
      acc[r].z = fmaf(xv[r].y, ws[1].z, acc[r].z);
      acc[r].w = fmaf(xv[r].y, ws[1].w, acc[r].w);
      acc[r].x = fmaf(xv[r].z, ws[2].x, acc[r].x);
      acc[r].y = fmaf(xv[r].z, ws[2].y, acc[r].y);
      acc[r].z = fmaf(xv[r].z, ws[2].z, acc[r].z);
      acc[r].w = fmaf(xv[r].z, ws[2].w, acc[r].w);
      acc[r].x = fmaf(xv[r].w, ws[3].x, acc[r].x);
      acc[r].y = fmaf(xv[r].w, ws[3].y, acc[r].y);
      acc[r].z = fmaf(xv[r].w, ws[3].z, acc[r].z);
      acc[r].w = fmaf(xv[r].w, ws[3].w, acc[r].w);
    }
  }

  const float4 bv = *(const float4*)&b1[4 * tx];
#pragma unroll
  for (int r = 0; r < 4; ++r) {
    int row = row_base + r;
    if (row < M) {
      float4 o;
      o.x = fmaxf(acc[r].x + bv.x, 0.f);
      o.y = fmaxf(acc[r].y + bv.y, 0.f);
      o.z = fmaxf(acc[r].z + bv.z, 0.f);
      o.w = fmaxf(acc[r].w + bv.w, 0.f);
      *(float4*)&h[(long long)row * 64 + 4 * tx] = o;
    }
  }
}

// ---------------------------------------------------------------------------
// Fused dual-GEMM, layer 2: hn = h@W2n ; hs = h@W2s + b2.
// Thread tile 4 rows x 4 cols x 2 outputs; block tile 128 rows x 32 cols.
// ---------------------------------------------------------------------------
__global__ __launch_bounds__(256) void gemm2_k(
    const float* __restrict__ h, const float* __restrict__ W2n,
    const float* __restrict__ W2s, const float* __restrict__ b2,
    float* __restrict__ hn, float* __restrict__ hs, int M) {
  __shared__ float Wn[64 * 32];
  __shared__ float Ws[64 * 32];
  const int tid = threadIdx.x;
  for (int i = tid; i < 512; i += 256) {
    ((float4*)Wn)[i] = ((const float4*)W2n)[i];
    ((float4*)Ws)[i] = ((const float4*)W2s)[i];
  }
  __syncthreads();

  const int tx = tid & 7;   // cols 4tx..4tx+3 (32 cols)
  const int ty = tid >> 3;  // rows 4ty..4ty+3 within 128-row block tile
  const int row_base = blockIdx.x * 128 + ty * 4;

  long long rr[4];
#pragma unroll
  for (int r = 0; r < 4; ++r) {
    int rowr = row_base + r;
    rr[r] = rowr < M ? rowr : (M - 1);
  }
  const float4* hp[4];
#pragma unroll
  for (int r = 0; r < 4; ++r) hp[r] = (const float4*)(h + rr[r] * 64);

  float4 an[4], as[4];
#pragma unroll
  for (int r = 0; r < 4; ++r) {
    an[r] = make_float4(0.f, 0.f, 0.f, 0.f);
    as[r] = make_float4(0.f, 0.f, 0.f, 0.f);
  }

#pragma unroll
  for (int k4 = 0; k4 < 16; ++k4) {
    float4 hv[4];
#pragma unroll
    for (int r = 0; r < 4; ++r) hv[r] = hp[r][k4];
    float4 wn[4], ws[4];
#pragma unroll
    for (int kk = 0; kk < 4; ++kk) {
      wn[kk] = *(const float4*)&Wn[(4 * k4 + kk) * 32 + 4 * tx];
      ws[kk] = *(const float4*)&Ws[(4 * k4 + kk) * 32 + 4 * tx];
    }
#pragma unroll
    for (int r = 0; r < 4; ++r) {
      float hk0 = hv[r].x, hk1 = hv[r].y, hk2 = hv[r].z, hk3 = hv[r].w;
      an[r].x = fmaf(hk0, wn[0].x, an[r].x);
      an[r].y = fmaf(hk0, wn[0].y, an[r].y);
      an[r].z = fmaf(hk0, wn[0].z, an[r].z);
      an[r].w = fmaf(hk0, wn[0].w, an[r].w);
      an[r].x = fmaf(hk1, wn[1].x, an[r].x);
      an[r].y = fmaf(hk1, wn[1].y, an[r].y);
      an[r].z = fmaf(hk1, wn[1].z, an[r].z);
      an[r].w = fmaf(hk1, wn[1].w, an[r].w);
      an[r].x = fmaf(hk2, wn[2].x, an[r].x);
      an[r].y = fmaf(hk2, wn[2].y, an[r].y);
      an[r].z = fmaf(hk2, wn[2].z, an[r].z);
      an[r].w = fmaf(hk2, wn[2].w, an[r].w);
      an[r].x = fmaf(hk3, wn[3].x, an[r].x);
      an[r].y = fmaf(hk3, wn[3].y, an[r].y);
      an[r].z = fmaf(hk3, wn[3].z, an[r].z);
      an[r].w = fmaf(hk3, wn[3].w, an[r].w);
      as[r].x = fmaf(hk0, ws[0].x, as[r].x);
      as[r].y = fmaf(hk0, ws[0].y, as[r].y);
      as[r].z = fmaf(hk0, ws[0].z, as[r].z);
      as[r].w = fmaf(hk0, ws[0].w, as[r].w);
      as[r].x = fmaf(hk1, ws[1].x, as[r].x);
      as[r].y = fmaf(hk1, ws[1].y, as[r].y);
      as[r].z = fmaf(hk1, ws[1].z, as[r].z);
      as[r].w = fmaf(hk1, ws[1].w, as[r].w);
      as[r].x = fmaf(hk2, ws[2].x, as[r].x);
      as[r].y = fmaf(hk2, ws[2].y, as[r].y);
      as[r].z = fmaf(hk2, ws[2].z, as[r].z);
      as[r].w = fmaf(hk2, ws[2].w, as[r].w);
      as[r].x = fmaf(hk3, ws[3].x, as[r].x);
      as[r].y = fmaf(hk3, ws[3].y, as[r].y);
      as[r].z = fmaf(hk3, ws[3].z, as[r].z);
      as[r].w = fmaf(hk3, ws[3].w, as[r].w);
    }
  }

  const float4 bv = *(const float4*)&b2[4 * tx];
#pragma unroll
  for (int r = 0; r < 4; ++r) {
    int row = row_base + r;
    if (row < M) {
      *(float4*)&hn[(long long)row * 32 + 4 * tx] = an[r];
      float4 o;
      o.x = as[r].x + bv.x;
      o.y = as[r].y + bv.y;
      o.z = as[r].z + bv.z;
      o.w = as[r].w + bv.w;
      *(float4*)&hs[(long long)row * 32 + 4 * tx] = o;
    }
  }
}

// ------------------------- phase 1: coarse buckets -------------------------
__global__ __launch_bounds__(1024) void bhist_k(const int* __restrict__ dst,
                                                unsigned* __restrict__ bcnt,
                                                int E) {
  __shared__ unsigned lh[NB];
  for (int i = threadIdx.x; i < NB; i += 1024) lh[i] = 0;
  __syncthreads();
  const int base = blockIdx.x * 16384;
#pragma unroll
  for (int it = 0; it < 16; ++it) {
    int e = base + it * 1024 + threadIdx.x;
    if (e < E) atomicAdd(&lh[((unsigned)dst[e]) >> BSH], 1u);
  }
  __syncthreads();
  for (int i = threadIdx.x; i < NB; i += 1024)
    if (lh[i]) atomicAdd(&bcnt[i], lh[i]);
}

__global__ __launch_bounds__(1024) void bscan_k(const unsigned* __restrict__ bcnt,
                                                unsigned* __restrict__ boff,
                                                unsigned* __restrict__ bcur) {
  __shared__ unsigned s[1024];
  const int tid = threadIdx.x;
  unsigned v = (tid < NB) ? bcnt[tid] : 0u;
  s[tid] = v;
  __syncthreads();
  for (int off = 1; off < 1024; off <<= 1) {
    unsigned t = (tid >= off) ? s[tid - off] : 0u;
    __syncthreads();
    s[tid] += t;
    __syncthreads();
  }
  unsigned ex = s[tid] - v;
  if (tid < NB) {
    boff[tid] = ex;
    bcur[tid] = ex;
  }
  if (tid == NB - 1) boff[NB] = ex + v;
}

// Scatter packed edges (src<<7 | dst&127) into bucket-ordered ep[].
// Each block reserves a contiguous run per bucket -> block-private write runs.
__global__ __launch_bounds__(1024) void bscatter_k(const int* __restrict__ src,
                                                   const int* __restrict__ dst,
                                                   unsigned* __restrict__ bcur,
                                                   unsigned* __restrict__ ep,
                                                   int E) {
  __shared__ unsigned lh[NB];
  __shared__ unsigned lbase[NB];
  for (int i = threadIdx.x; i < NB; i += 1024) lh[i] = 0;
  __syncthreads();
  const int base = blockIdx.x * 16384;
  unsigned short rank[16];
  unsigned short bb[16];
#pragma unroll
  for (int it = 0; it < 16; ++it) {
    int e = base + it * 1024 + threadIdx.x;
    if (e < E) {
      unsigned b = ((unsigned)dst[e]) >> BSH;
      bb[it] = (unsigned short)b;
      rank[it] = (unsigned short)atomicAdd(&lh[b], 1u);
    }
  }
  __syncthreads();
  for (int i = threadIdx.x; i < NB; i += 1024)
    lbase[i] = lh[i] ? atomicAdd(&bcur[i], lh[i]) : 0u;
  __syncthreads();
#pragma unroll
  for (int it = 0; it < 16; ++it) {
    int e = base + it * 1024 + threadIdx.x;
    if (e < E) {
      unsigned b = bb[it];
      ep[lbase[b] + rank[it]] =
          (((unsigned)src[e]) << BSH) | (((unsigned)dst[e]) & BMASK);
    }
  }
}

// ------------------------- phase 2: in-bucket sort -------------------------
__global__ __launch_bounds__(256) void bsort_k(const unsigned* __restrict__ ep,
                                               const unsigned* __restrict__ boff,
                                               int* __restrict__ ssrc,
                                               unsigned* __restrict__ rows) {
  __shared__ unsigned cnt[128];
  __shared__ unsigned sc[128];
  const int tid = threadIdx.x;
  const unsigned beg = boff[blockIdx.x], end = boff[blockIdx.x + 1];
  if (tid < 128) cnt[tid] = 0;
  __syncthreads();
  for (unsigned j = beg + tid; j < end; j += 256)
    atomicAdd(&cnt[ep[j] & BMASK], 1u);
  __syncthreads();
  unsigned v = (tid < 128) ? cnt[tid] : 0u;
  if (tid < 128) sc[tid] = v;
  __syncthreads();
  for (int off = 1; off < 128; off <<= 1) {
    unsigned t = (tid < 128 && tid >= off) ? sc[tid - off] : 0u;
    __syncthreads();
    if (tid < 128) sc[tid] += t;
    __syncthreads();
  }
  unsigned ex = sc[tid] - v;
  if (tid < 128) {
    rows[blockIdx.x * 128 + tid] = beg + ex;
    cnt[tid] = ex;
  }
  __syncthreads();
  for (unsigned j = beg + tid; j < end; j += 256) {
    unsigned p = ep[j];
    unsigned r = atomicAdd(&cnt[p & BMASK], 1u);
    ssrc[beg + r] = (int)(p >> BSH);
  }
}

// ---------------------------------------------------------------------------
// Gather-mean, 8 clamped loads always in flight (deg~16, latency-bound):
//   out[node][f] = (1/deg)*sum_j val[ssrc[j]][f]  (+ base[node][f])
// ---------------------------------------------------------------------------
template <int LOGF, bool ADD_BASE>
__global__ __launch_bounds__(256) void gather_k(
    const float* __restrict__ val, const int* __restrict__ ssrc,
    const unsigned* __restrict__ rows, const float* __restrict__ base,
    float* __restrict__ out, int N) {
  constexpr int F = 1 << LOGF;
  const int node = blockIdx.x * (256 >> LOGF) + (threadIdx.x >> LOGF);
  const int f = threadIdx.x & (F - 1);
  if (node >= N) return;
  const unsigned beg = rows[node], end = rows[node + 1];
  float acc = 0.f;
  if (end > beg) {
    const unsigned last = end - 1;
    for (unsigned j = beg; j < end; j += 8) {
      float s = 0.f;
#pragma unroll
      for (int i = 0; i < 8; ++i) {
        unsigned jj = j + i;
        unsigned idx = jj < last ? jj : last;  // clamp: load always issued
        int sn = ssrc[idx];
        float vv = val[((size_t)sn << LOGF) | f];
        s += (jj < end) ? vv : 0.f;            // predicate the add only
      }
      acc += s;
    }
  }
  const unsigned dg = end - beg;
  const float inv = dg ? 1.f / (float)dg : 0.f;
  float v = acc * inv;
  if (ADD_BASE) v += base[((size_t)node << LOGF) | f];
  out[((size_t)node << LOGF) | f] = v;
}

extern "C" void kernel_launch(void* const* d_in, const int* in_sizes, int n_in,
                              void* d_out, int out_size, void* d_ws,
                              size_t ws_size, hipStream_t stream) {
  const float* x   = (const float*)d_in[0];
  const int*   ei  = (const int*)d_in[1];  // [2, E]: row0 = src, row1 = dst
  const float* W1n = (const float*)d_in[2];
  const float* W1s = (const float*)d_in[3];
  const float* b1  = (const float*)d_in[4];
  const float* W2n = (const float*)d_in[5];
  const float* W2s = (const float*)d_in[6];
  const float* b2  = (const float*)d_in[7];
  float* out = (float*)d_out;

  const int E = in_sizes[1] / 2;  // 1,600,000
  const int M = N_NODES;
  const int* src = ei;
  const int* dst = ei + E;

  // Workspace layout (bytes):
  //   ep    @ 0           6,400,000
  //   ssrc  @ 6,400,000   6,400,000
  //   rows  @ 12,800,000    401,412  ((NPAD+1) u32)
  //   bcnt  @ 13,203,456      3,136
  //   boff  @ 13,207,552      3,140
  //   bcur  @ 13,211,648      3,136
  //   mean1 @ 13,215,744 25,600,000  (layer2: hn @13,215,744, hs @26,015,744)
  //   h     @ 38,815,744 25,600,000
  char* wsb = (char*)d_ws;
  unsigned* ep    = (unsigned*)(wsb);
  int*      ssrc  = (int*)(wsb + 6400000);
  unsigned* rows  = (unsigned*)(wsb + 12800000);
  unsigned* bcnt  = (unsigned*)(wsb + 13203456);
  unsigned* boff  = (unsigned*)(wsb + 13207552);
  unsigned* bcur  = (unsigned*)(wsb + 13211648);
  float*    mean1 = (float*)(wsb + 13215744);
  float*    h     = (float*)(wsb + 38815744);
  float* hn = (float*)(wsb + 13215744);  // [M x 32]
  float* hs = (float*)(wsb + 26015744);  // [M x 32]

  const int EB = (E + 16383) / 16384;  // 98

  // ---- dst-sorted edge list (CSR), block-private writes only ----
  hipMemsetAsync(bcnt, 0, NB * 4, stream);
  bhist_k<<<EB, 1024, 0, stream>>>(dst, bcnt, E);
  bscan_k<<<1, 1024, 0, stream>>>(bcnt, boff, bcur);
  bscatter_k<<<EB, 1024, 0, stream>>>(src, dst, bcur, ep, E);
  bsort_k<<<NB, 256, 0, stream>>>(ep, boff, ssrc, rows);

  // ---- Layer 1: mean1 = mean(x[src]) ; h = relu(mean1@W1n + x@W1s + b1) ----
  gather_k<6, false><<<M / 4, 256, 0, stream>>>(x, ssrc, rows, nullptr, mean1, M);
  gemm1_k<<<(M + 63) / 64, 256, 0, stream>>>(mean1, x, W1n, W1s, b1, h, M);

  // ---- Layer 2: hn/hs = h@{W2n,W2s}+b2 ; out = mean(hn[src]) + hs ----
  gemm2_k<<<(M + 127) / 128, 256, 0, stream>>>(h, W2n, W2s, b2, hn, hs, M);
  gather_k<5, true><<<M / 8, 256, 0, stream>>>(hn, ssrc, rows, hs, out, M);
}

// Round 7
// 269.726 us; speedup vs baseline: 4.8251x; 4.8251x over previous
//
#include <hip/hip_runtime.h>
#include <hip/hip_bf16.h>

#define N_NODES 100000
#define NB 784   // buckets of 128 nodes: 784*128 = 100352 >= N_NODES
#define NPAD 100352
#define BSH 7
#define BMASK 127
#define APAD 68  // padded LDS row stride (floats): 16B-aligned, breaks bank stride

__device__ inline void fma4(float a, const float4& w, float4& c) {
  c.x = fmaf(a, w.x, c.x);
  c.y = fmaf(a, w.y, c.y);
  c.z = fmaf(a, w.z, c.z);
  c.w = fmaf(a, w.w, c.w);
}

// ---------------------------------------------------------------------------
// Fused dual-GEMM, layer 1:
//   h[r][c] = relu( mean1[r]@W1n[:,c] + x[r]@W1s[:,c] + b1[c] )
// Block tile 64 rows x 64 cols; thread tile 4x4. A staged in LDS (coalesced,
// each element loaded once), W in LDS; inner loop reads LDS only + phase-split
// + unroll 1 => ~70 live VGPRs, no spill (R6 spilled at 256 with global-fed A).
// ---------------------------------------------------------------------------
__global__ __launch_bounds__(256) void gemm1_k(
    const float* __restrict__ mean1, const float* __restrict__ x,
    const float* __restrict__ W1n, const float* __restrict__ W1s,
    const float* __restrict__ b1, float* __restrict__ h, int M) {
  __shared__ float Wn[64 * 64];
  __shared__ float Ws[64 * 64];
  __shared__ float Am[64 * APAD];
  __shared__ float Ax[64 * APAD];
  const int tid = threadIdx.x;
  const int row0 = blockIdx.x * 64;

  for (int i = tid; i < 1024; i += 256) {
    ((float4*)Wn)[i] = ((const float4*)W1n)[i];
    ((float4*)Ws)[i] = ((const float4*)W1s)[i];
  }
  for (int i = tid; i < 1024; i += 256) {
    int r = i >> 4, c = i & 15;
    long long gr = row0 + r;
    if (gr >= M) gr = M - 1;
    float4 mv = ((const float4*)(mean1 + gr * 64))[c];
    float4 xv = ((const float4*)(x + gr * 64))[c];
    *(float4*)&Am[r * APAD + 4 * c] = mv;
    *(float4*)&Ax[r * APAD + 4 * c] = xv;
  }
  __syncthreads();

  const int tx = tid & 15;  // cols 4tx..4tx+3
  const int ty = tid >> 4;  // rows 4ty..4ty+3
  const int arow = ty * 4;

  float4 acc[4];
#pragma unroll
  for (int r = 0; r < 4; ++r) acc[r] = make_float4(0.f, 0.f, 0.f, 0.f);

#pragma unroll 1
  for (int k4 = 0; k4 < 16; ++k4) {
    // phase 1: mean1 @ W1n
    {
      float4 w0 = *(const float4*)&Wn[(4 * k4 + 0) * 64 + 4 * tx];
      float4 w1 = *(const float4*)&Wn[(4 * k4 + 1) * 64 + 4 * tx];
      float4 w2 = *(const float4*)&Wn[(4 * k4 + 2) * 64 + 4 * tx];
      float4 w3 = *(const float4*)&Wn[(4 * k4 + 3) * 64 + 4 * tx];
#pragma unroll
      for (int r = 0; r < 4; ++r) {
        float4 a = *(const float4*)&Am[(arow + r) * APAD + 4 * k4];
        fma4(a.x, w0, acc[r]);
        fma4(a.y, w1, acc[r]);
        fma4(a.z, w2, acc[r]);
        fma4(a.w, w3, acc[r]);
      }
    }
    // phase 2: x @ W1s
    {
      float4 w0 = *(const float4*)&Ws[(4 * k4 + 0) * 64 + 4 * tx];
      float4 w1 = *(const float4*)&Ws[(4 * k4 + 1) * 64 + 4 * tx];
      float4 w2 = *(const float4*)&Ws[(4 * k4 + 2) * 64 + 4 * tx];
      float4 w3 = *(const float4*)&Ws[(4 * k4 + 3) * 64 + 4 * tx];
#pragma unroll
      for (int r = 0; r < 4; ++r) {
        float4 a = *(const float4*)&Ax[(arow + r) * APAD + 4 * k4];
        fma4(a.x, w0, acc[r]);
        fma4(a.y, w1, acc[r]);
        fma4(a.z, w2, acc[r]);
        fma4(a.w, w3, acc[r]);
      }
    }
  }

  const float4 bv = *(const float4*)&b1[4 * tx];
#pragma unroll
  for (int r = 0; r < 4; ++r) {
    int row = row0 + arow + r;
    if (row < M) {
      float4 o;
      o.x = fmaxf(acc[r].x + bv.x, 0.f);
      o.y = fmaxf(acc[r].y + bv.y, 0.f);
      o.z = fmaxf(acc[r].z + bv.z, 0.f);
      o.w = fmaxf(acc[r].w + bv.w, 0.f);
      *(float4*)&h[(long long)row * 64 + 4 * tx] = o;
    }
  }
}

// ---------------------------------------------------------------------------
// Fused dual-GEMM, layer 2: hn = h@W2n ; hs = h@W2s + b2.
// Block tile 128 rows x 32 cols; thread tile 4x4x2; h staged in LDS.
// ---------------------------------------------------------------------------
__global__ __launch_bounds__(256) void gemm2_k(
    const float* __restrict__ h, const float* __restrict__ W2n,
    const float* __restrict__ W2s, const float* __restrict__ b2,
    float* __restrict__ hn, float* __restrict__ hs, int M) {
  __shared__ float Wn[64 * 32];
  __shared__ float Ws[64 * 32];
  __shared__ float Ah[128 * APAD];
  const int tid = threadIdx.x;
  const int row0 = blockIdx.x * 128;

  for (int i = tid; i < 512; i += 256) {
    ((float4*)Wn)[i] = ((const float4*)W2n)[i];
    ((float4*)Ws)[i] = ((const float4*)W2s)[i];
  }
  for (int i = tid; i < 2048; i += 256) {
    int r = i >> 4, c = i & 15;
    long long gr = row0 + r;
    if (gr >= M) gr = M - 1;
    float4 v = ((const float4*)(h + gr * 64))[c];
    *(float4*)&Ah[r * APAD + 4 * c] = v;
  }
  __syncthreads();

  const int tx = tid & 7;   // cols 4tx..4tx+3 (32)
  const int ty = tid >> 3;  // rows 4ty..4ty+3 (128)
  const int arow = ty * 4;

  float4 an[4], as[4];
#pragma unroll
  for (int r = 0; r < 4; ++r) {
    an[r] = make_float4(0.f, 0.f, 0.f, 0.f);
    as[r] = make_float4(0.f, 0.f, 0.f, 0.f);
  }

#pragma unroll 1
  for (int k4 = 0; k4 < 16; ++k4) {
    float4 wn0 = *(const float4*)&Wn[(4 * k4 + 0) * 32 + 4 * tx];
    float4 wn1 = *(const float4*)&Wn[(4 * k4 + 1) * 32 + 4 * tx];
    float4 wn2 = *(const float4*)&Wn[(4 * k4 + 2) * 32 + 4 * tx];
    float4 wn3 = *(const float4*)&Wn[(4 * k4 + 3) * 32 + 4 * tx];
    float4 ws0 = *(const float4*)&Ws[(4 * k4 + 0) * 32 + 4 * tx];
    float4 ws1 = *(const float4*)&Ws[(4 * k4 + 1) * 32 + 4 * tx];
    float4 ws2 = *(const float4*)&Ws[(4 * k4 + 2) * 32 + 4 * tx];
    float4 ws3 = *(const float4*)&Ws[(4 * k4 + 3) * 32 + 4 * tx];
#pragma unroll
    for (int r = 0; r < 4; ++r) {
      float4 a = *(const float4*)&Ah[(arow + r) * APAD + 4 * k4];
      fma4(a.x, wn0, an[r]);
      fma4(a.y, wn1, an[r]);
      fma4(a.z, wn2, an[r]);
      fma4(a.w, wn3, an[r]);
      fma4(a.x, ws0, as[r]);
      fma4(a.y, ws1, as[r]);
      fma4(a.z, ws2, as[r]);
      fma4(a.w, ws3, as[r]);
    }
  }

  const float4 bv = *(const float4*)&b2[4 * tx];
#pragma unroll
  for (int r = 0; r < 4; ++r) {
    int row = row0 + arow + r;
    if (row < M) {
      *(float4*)&hn[(long long)row * 32 + 4 * tx] = an[r];
      float4 o;
      o.x = as[r].x + bv.x;
      o.y = as[r].y + bv.y;
      o.z = as[r].z + bv.z;
      o.w = as[r].w + bv.w;
      *(float4*)&hs[(long long)row * 32 + 4 * tx] = o;
    }
  }
}

// ------------------------- phase 1: coarse buckets -------------------------
__global__ __launch_bounds__(1024) void bhist_k(const int* __restrict__ dst,
                                                unsigned* __restrict__ bcnt,
                                                int E) {
  __shared__ unsigned lh[NB];
  for (int i = threadIdx.x; i < NB; i += 1024) lh[i] = 0;
  __syncthreads();
  const int base = blockIdx.x * 16384;
#pragma unroll
  for (int it = 0; it < 16; ++it) {
    int e = base + it * 1024 + threadIdx.x;
    if (e < E) atomicAdd(&lh[((unsigned)dst[e]) >> BSH], 1u);
  }
  __syncthreads();
  for (int i = threadIdx.x; i < NB; i += 1024)
    if (lh[i]) atomicAdd(&bcnt[i], lh[i]);
}

__global__ __launch_bounds__(1024) void bscan_k(const unsigned* __restrict__ bcnt,
                                                unsigned* __restrict__ boff,
                                                unsigned* __restrict__ bcur) {
  __shared__ unsigned s[1024];
  const int tid = threadIdx.x;
  unsigned v = (tid < NB) ? bcnt[tid] : 0u;
  s[tid] = v;
  __syncthreads();
  for (int off = 1; off < 1024; off <<= 1) {
    unsigned t = (tid >= off) ? s[tid - off] : 0u;
    __syncthreads();
    s[tid] += t;
    __syncthreads();
  }
  unsigned ex = s[tid] - v;
  if (tid < NB) {
    boff[tid] = ex;
    bcur[tid] = ex;
  }
  if (tid == NB - 1) boff[NB] = ex + v;
}

// Scatter packed edges (src<<7 | dst&127) into bucket-ordered ep[].
__global__ __launch_bounds__(1024) void bscatter_k(const int* __restrict__ src,
                                                   const int* __restrict__ dst,
                                                   unsigned* __restrict__ bcur,
                                                   unsigned* __restrict__ ep,
                                                   int E) {
  __shared__ unsigned lh[NB];
  __shared__ unsigned lbase[NB];
  for (int i = threadIdx.x; i < NB; i += 1024) lh[i] = 0;
  __syncthreads();
  const int base = blockIdx.x * 16384;
  unsigned short rank[16];
  unsigned short bb[16];
#pragma unroll
  for (int it = 0; it < 16; ++it) {
    int e = base + it * 1024 + threadIdx.x;
    if (e < E) {
      unsigned b = ((unsigned)dst[e]) >> BSH;
      bb[it] = (unsigned short)b;
      rank[it] = (unsigned short)atomicAdd(&lh[b], 1u);
    }
  }
  __syncthreads();
  for (int i = threadIdx.x; i < NB; i += 1024)
    lbase[i] = lh[i] ? atomicAdd(&bcur[i], lh[i]) : 0u;
  __syncthreads();
#pragma unroll
  for (int it = 0; it < 16; ++it) {
    int e = base + it * 1024 + threadIdx.x;
    if (e < E) {
      unsigned b = bb[it];
      ep[lbase[b] + rank[it]] =
          (((unsigned)src[e]) << BSH) | (((unsigned)dst[e]) & BMASK);
    }
  }
}

// ------------------------- phase 2: in-bucket sort -------------------------
__global__ __launch_bounds__(256) void bsort_k(const unsigned* __restrict__ ep,
                                               const unsigned* __restrict__ boff,
                                               int* __restrict__ ssrc,
                                               unsigned* __restrict__ rows) {
  __shared__ unsigned cnt[128];
  __shared__ unsigned sc[128];
  const int tid = threadIdx.x;
  const unsigned beg = boff[blockIdx.x], end = boff[blockIdx.x + 1];
  if (tid < 128) cnt[tid] = 0;
  __syncthreads();
  for (unsigned j = beg + tid; j < end; j += 256)
    atomicAdd(&cnt[ep[j] & BMASK], 1u);
  __syncthreads();
  unsigned v = (tid < 128) ? cnt[tid] : 0u;
  if (tid < 128) sc[tid] = v;
  __syncthreads();
  for (int off = 1; off < 128; off <<= 1) {
    unsigned t = (tid < 128 && tid >= off) ? sc[tid - off] : 0u;
    __syncthreads();
    if (tid < 128) sc[tid] += t;
    __syncthreads();
  }
  unsigned ex = sc[tid] - v;
  if (tid < 128) {
    rows[blockIdx.x * 128 + tid] = beg + ex;
    cnt[tid] = ex;
  }
  __syncthreads();
  for (unsigned j = beg + tid; j < end; j += 256) {
    unsigned p = ep[j];
    unsigned r = atomicAdd(&cnt[p & BMASK], 1u);
    ssrc[beg + r] = (int)(p >> BSH);
  }
}

// ---------------------------------------------------------------------------
// Gather-mean, 8 clamped loads always in flight (deg~16, latency-bound):
//   out[node][f] = (1/deg)*sum_j val[ssrc[j]][f]  (+ base[node][f])
// ---------------------------------------------------------------------------
template <int LOGF, bool ADD_BASE>
__global__ __launch_bounds__(256) void gather_k(
    const float* __restrict__ val, const int* __restrict__ ssrc,
    const unsigned* __restrict__ rows, const float* __restrict__ base,
    float* __restrict__ out, int N) {
  constexpr int F = 1 << LOGF;
  const int node = blockIdx.x * (256 >> LOGF) + (threadIdx.x >> LOGF);
  const int f = threadIdx.x & (F - 1);
  if (node >= N) return;
  const unsigned beg = rows[node], end = rows[node + 1];
  float acc = 0.f;
  if (end > beg) {
    const unsigned last = end - 1;
    for (unsigned j = beg; j < end; j += 8) {
      float s = 0.f;
#pragma unroll
      for (int i = 0; i < 8; ++i) {
        unsigned jj = j + i;
        unsigned idx = jj < last ? jj : last;  // clamp: load always issued
        int sn = ssrc[idx];
        float vv = val[((size_t)sn << LOGF) | f];
        s += (jj < end) ? vv : 0.f;            // predicate the add only
      }
      acc += s;
    }
  }
  const unsigned dg = end - beg;
  const float inv = dg ? 1.f / (float)dg : 0.f;
  float v = acc * inv;
  if (ADD_BASE) v += base[((size_t)node << LOGF) | f];
  out[((size_t)node << LOGF) | f] = v;
}

extern "C" void kernel_launch(void* const* d_in, const int* in_sizes, int n_in,
                              void* d_out, int out_size, void* d_ws,
                              size_t ws_size, hipStream_t stream) {
  const float* x   = (const float*)d_in[0];
  const int*   ei  = (const int*)d_in[1];  // [2, E]: row0 = src, row1 = dst
  const float* W1n = (const float*)d_in[2];
  const float* W1s = (const float*)d_in[3];
  const float* b1  = (const float*)d_in[4];
  const float* W2n = (const float*)d_in[5];
  const float* W2s = (const float*)d_in[6];
  const float* b2  = (const float*)d_in[7];
  float* out = (float*)d_out;

  const int E = in_sizes[1] / 2;  // 1,600,000
  const int M = N_NODES;
  const int* src = ei;
  const int* dst = ei + E;

  // Workspace layout (bytes):
  //   ep    @ 0           6,400,000
  //   ssrc  @ 6,400,000   6,400,000
  //   rows  @ 12,800,000    401,412  ((NPAD+1) u32)
  //   bcnt  @ 13,203,456      3,136
  //   boff  @ 13,207,552      3,140
  //   bcur  @ 13,211,648      3,136
  //   mean1 @ 13,215,744 25,600,000  (layer2: hn @13,215,744, hs @26,015,744)
  //   h     @ 38,815,744 25,600,000
  char* wsb = (char*)d_ws;
  unsigned* ep    = (unsigned*)(wsb);
  int*      ssrc  = (int*)(wsb + 6400000);
  unsigned* rows  = (unsigned*)(wsb + 12800000);
  unsigned* bcnt  = (unsigned*)(wsb + 13203456);
  unsigned* boff  = (unsigned*)(wsb + 13207552);
  unsigned* bcur  = (unsigned*)(wsb + 13211648);
  float*    mean1 = (float*)(wsb + 13215744);
  float*    h     = (float*)(wsb + 38815744);
  float* hn = (float*)(wsb + 13215744);  // [M x 32]
  float* hs = (float*)(wsb + 26015744);  // [M x 32]

  const int EB = (E + 16383) / 16384;  // 98

  // ---- dst-sorted edge list (CSR), block-private writes only ----
  hipMemsetAsync(bcnt, 0, NB * 4, stream);
  bhist_k<<<EB, 1024, 0, stream>>>(dst, bcnt, E);
  bscan_k<<<1, 1024, 0, stream>>>(bcnt, boff, bcur);
  bscatter_k<<<EB, 1024, 0, stream>>>(src, dst, bcur, ep, E);
  bsort_k<<<NB, 256, 0, stream>>>(ep, boff, ssrc, rows);

  // ---- Layer 1: mean1 = mean(x[src]) ; h = relu(mean1@W1n + x@W1s + b1) ----
  gather_k<6, false><<<M / 4, 256, 0, stream>>>(x, ssrc, rows, nullptr, mean1, M);
  gemm1_k<<<(M + 63) / 64, 256, 0, stream>>>(mean1, x, W1n, W1s, b1, h, M);

  // ---- Layer 2: hn/hs = h@{W2n,W2s}+b2 ; out = mean(hn[src]) + hs ----
  gemm2_k<<<(M + 127) / 128, 256, 0, stream>>>(h, W2n, W2s, b2, hn, hs, M);
  gather_k<5, true><<<M / 8, 256, 0, stream>>>(hn, ssrc, rows, hs, out, M);
}

// Round 8
// 236.105 us; speedup vs baseline: 5.5122x; 1.1424x over previous
//
#include <hip/hip_runtime.h>
#include <hip/hip_bf16.h>

#define N_NODES 100000
#define NB 784   // buckets of 128 nodes: 784*128 = 100352 >= N_NODES
#define NPAD 100352
#define BSH 7
#define BMASK 127
#define APAD 68  // padded LDS row stride (floats)

__device__ inline void fma4(float a, const float4& w, float4& c) {
  c.x = fmaf(a, w.x, c.x);
  c.y = fmaf(a, w.y, c.y);
  c.z = fmaf(a, w.z, c.z);
  c.w = fmaf(a, w.w, c.w);
}
__device__ inline unsigned short f2bf(float f) {  // RNE f32->bf16
  unsigned u = __float_as_uint(f);
  u += 0x7fffu + ((u >> 16) & 1u);
  return (unsigned short)(u >> 16);
}
__device__ inline float bflo(unsigned u) { return __uint_as_float(u << 16); }
__device__ inline float bfhi(unsigned u) { return __uint_as_float(u & 0xffff0000u); }

// ---------------------------------------------------------------------------
// Layer-1 dual-GEMM over x:  xn = x@W1n (bf16 out),  xs = x@W1s + b1 (f32).
// Block tile 64r x 64c, thread tile 4x4x2; A staged in LDS (R7-proven shape).
// ---------------------------------------------------------------------------
__global__ __launch_bounds__(256) void gemm1_k(
    const float* __restrict__ x, const float* __restrict__ W1n,
    const float* __restrict__ W1s, const float* __restrict__ b1,
    unsigned short* __restrict__ xnb, float* __restrict__ xs, int M) {
  __shared__ float Wn[64 * 64];
  __shared__ float Ws[64 * 64];
  __shared__ float Ax[64 * APAD];
  const int tid = threadIdx.x;
  const int row0 = blockIdx.x * 64;

  for (int i = tid; i < 1024; i += 256) {
    ((float4*)Wn)[i] = ((const float4*)W1n)[i];
    ((float4*)Ws)[i] = ((const float4*)W1s)[i];
  }
  for (int i = tid; i < 1024; i += 256) {
    int r = i >> 4, c = i & 15;
    long long gr = row0 + r;
    if (gr >= M) gr = M - 1;
    float4 v = ((const float4*)(x + gr * 64))[c];
    *(float4*)&Ax[r * APAD + 4 * c] = v;
  }
  __syncthreads();

  const int tx = tid & 15;
  const int ty = tid >> 4;
  const int arow = ty * 4;

  float4 an[4], as[4];
#pragma unroll
  for (int r = 0; r < 4; ++r) {
    an[r] = make_float4(0.f, 0.f, 0.f, 0.f);
    as[r] = make_float4(0.f, 0.f, 0.f, 0.f);
  }

#pragma unroll 1
  for (int k4 = 0; k4 < 16; ++k4) {
    float4 wn0 = *(const float4*)&Wn[(4 * k4 + 0) * 64 + 4 * tx];
    float4 wn1 = *(const float4*)&Wn[(4 * k4 + 1) * 64 + 4 * tx];
    float4 wn2 = *(const float4*)&Wn[(4 * k4 + 2) * 64 + 4 * tx];
    float4 wn3 = *(const float4*)&Wn[(4 * k4 + 3) * 64 + 4 * tx];
    float4 ws0 = *(const float4*)&Ws[(4 * k4 + 0) * 64 + 4 * tx];
    float4 ws1 = *(const float4*)&Ws[(4 * k4 + 1) * 64 + 4 * tx];
    float4 ws2 = *(const float4*)&Ws[(4 * k4 + 2) * 64 + 4 * tx];
    float4 ws3 = *(const float4*)&Ws[(4 * k4 + 3) * 64 + 4 * tx];
#pragma unroll
    for (int r = 0; r < 4; ++r) {
      float4 a = *(const float4*)&Ax[(arow + r) * APAD + 4 * k4];
      fma4(a.x, wn0, an[r]);
      fma4(a.y, wn1, an[r]);
      fma4(a.z, wn2, an[r]);
      fma4(a.w, wn3, an[r]);
      fma4(a.x, ws0, as[r]);
      fma4(a.y, ws1, as[r]);
      fma4(a.z, ws2, as[r]);
      fma4(a.w, ws3, as[r]);
    }
  }

  const float4 bv = *(const float4*)&b1[4 * tx];
#pragma unroll
  for (int r = 0; r < 4; ++r) {
    int row = row0 + arow + r;
    if (row < M) {
      float4 o;
      o.x = as[r].x + bv.x;
      o.y = as[r].y + bv.y;
      o.z = as[r].z + bv.z;
      o.w = as[r].w + bv.w;
      *(float4*)&xs[(long long)row * 64 + 4 * tx] = o;
      ushort4 p;
      p.x = f2bf(an[r].x);
      p.y = f2bf(an[r].y);
      p.z = f2bf(an[r].z);
      p.w = f2bf(an[r].w);
      *(ushort4*)&xnb[(long long)row * 64 + 4 * tx] = p;
    }
  }
}

// ---------------------------------------------------------------------------
// Layer-2 dual-GEMM over h: hn = h@W2n (bf16 out), hs = h@W2s + b2 (f32).
// Block tile 128r x 32c, thread tile 4x4x2; h staged in LDS.
// ---------------------------------------------------------------------------
__global__ __launch_bounds__(256) void gemm2_k(
    const float* __restrict__ h, const float* __restrict__ W2n,
    const float* __restrict__ W2s, const float* __restrict__ b2,
    unsigned short* __restrict__ hnb, float* __restrict__ hs, int M) {
  __shared__ float Wn[64 * 32];
  __shared__ float Ws[64 * 32];
  __shared__ float Ah[128 * APAD];
  const int tid = threadIdx.x;
  const int row0 = blockIdx.x * 128;

  for (int i = tid; i < 512; i += 256) {
    ((float4*)Wn)[i] = ((const float4*)W2n)[i];
    ((float4*)Ws)[i] = ((const float4*)W2s)[i];
  }
  for (int i = tid; i < 2048; i += 256) {
    int r = i >> 4, c = i & 15;
    long long gr = row0 + r;
    if (gr >= M) gr = M - 1;
    float4 v = ((const float4*)(h + gr * 64))[c];
    *(float4*)&Ah[r * APAD + 4 * c] = v;
  }
  __syncthreads();

  const int tx = tid & 7;
  const int ty = tid >> 3;
  const int arow = ty * 4;

  float4 an[4], as[4];
#pragma unroll
  for (int r = 0; r < 4; ++r) {
    an[r] = make_float4(0.f, 0.f, 0.f, 0.f);
    as[r] = make_float4(0.f, 0.f, 0.f, 0.f);
  }

#pragma unroll 1
  for (int k4 = 0; k4 < 16; ++k4) {
    float4 wn0 = *(const float4*)&Wn[(4 * k4 + 0) * 32 + 4 * tx];
    float4 wn1 = *(const float4*)&Wn[(4 * k4 + 1) * 32 + 4 * tx];
    float4 wn2 = *(const float4*)&Wn[(4 * k4 + 2) * 32 + 4 * tx];
    float4 wn3 = *(const float4*)&Wn[(4 * k4 + 3) * 32 + 4 * tx];
    float4 ws0 = *(const float4*)&Ws[(4 * k4 + 0) * 32 + 4 * tx];
    float4 ws1 = *(const float4*)&Ws[(4 * k4 + 1) * 32 + 4 * tx];
    float4 ws2 = *(const float4*)&Ws[(4 * k4 + 2) * 32 + 4 * tx];
    float4 ws3 = *(const float4*)&Ws[(4 * k4 + 3) * 32 + 4 * tx];
#pragma unroll
    for (int r = 0; r < 4; ++r) {
      float4 a = *(const float4*)&Ah[(arow + r) * APAD + 4 * k4];
      fma4(a.x, wn0, an[r]);
      fma4(a.y, wn1, an[r]);
      fma4(a.z, wn2, an[r]);
      fma4(a.w, wn3, an[r]);
      fma4(a.x, ws0, as[r]);
      fma4(a.y, ws1, as[r]);
      fma4(a.z, ws2, as[r]);
      fma4(a.w, ws3, as[r]);
    }
  }

  const float4 bv = *(const float4*)&b2[4 * tx];
#pragma unroll
  for (int r = 0; r < 4; ++r) {
    int row = row0 + arow + r;
    if (row < M) {
      float4 o;
      o.x = as[r].x + bv.x;
      o.y = as[r].y + bv.y;
      o.z = as[r].z + bv.z;
      o.w = as[r].w + bv.w;
      *(float4*)&hs[(long long)row * 32 + 4 * tx] = o;
      ushort4 p;
      p.x = f2bf(an[r].x);
      p.y = f2bf(an[r].y);
      p.z = f2bf(an[r].z);
      p.w = f2bf(an[r].w);
      *(ushort4*)&hnb[(long long)row * 32 + 4 * tx] = p;
    }
  }
}

// ------------------------- phase 1: coarse buckets -------------------------
__global__ __launch_bounds__(1024) void bhist_k(const int* __restrict__ dst,
                                                unsigned* __restrict__ bcnt,
                                                int E) {
  __shared__ unsigned lh[NB];
  for (int i = threadIdx.x; i < NB; i += 1024) lh[i] = 0;
  __syncthreads();
  const int base = blockIdx.x * 16384;
#pragma unroll
  for (int it = 0; it < 16; ++it) {
    int e = base + it * 1024 + threadIdx.x;
    if (e < E) atomicAdd(&lh[((unsigned)dst[e]) >> BSH], 1u);
  }
  __syncthreads();
  for (int i = threadIdx.x; i < NB; i += 1024)
    if (lh[i]) atomicAdd(&bcnt[i], lh[i]);
}

__global__ __launch_bounds__(1024) void bscan_k(const unsigned* __restrict__ bcnt,
                                                unsigned* __restrict__ boff,
                                                unsigned* __restrict__ bcur) {
  __shared__ unsigned s[1024];
  const int tid = threadIdx.x;
  unsigned v = (tid < NB) ? bcnt[tid] : 0u;
  s[tid] = v;
  __syncthreads();
  for (int off = 1; off < 1024; off <<= 1) {
    unsigned t = (tid >= off) ? s[tid - off] : 0u;
    __syncthreads();
    s[tid] += t;
    __syncthreads();
  }
  unsigned ex = s[tid] - v;
  if (tid < NB) {
    boff[tid] = ex;
    bcur[tid] = ex;
  }
  if (tid == NB - 1) boff[NB] = ex + v;
}

__global__ __launch_bounds__(1024) void bscatter_k(const int* __restrict__ src,
                                                   const int* __restrict__ dst,
                                                   unsigned* __restrict__ bcur,
                                                   unsigned* __restrict__ ep,
                                                   int E) {
  __shared__ unsigned lh[NB];
  __shared__ unsigned lbase[NB];
  for (int i = threadIdx.x; i < NB; i += 1024) lh[i] = 0;
  __syncthreads();
  const int base = blockIdx.x * 16384;
  unsigned short rank[16];
  unsigned short bb[16];
#pragma unroll
  for (int it = 0; it < 16; ++it) {
    int e = base + it * 1024 + threadIdx.x;
    if (e < E) {
      unsigned b = ((unsigned)dst[e]) >> BSH;
      bb[it] = (unsigned short)b;
      rank[it] = (unsigned short)atomicAdd(&lh[b], 1u);
    }
  }
  __syncthreads();
  for (int i = threadIdx.x; i < NB; i += 1024)
    lbase[i] = lh[i] ? atomicAdd(&bcur[i], lh[i]) : 0u;
  __syncthreads();
#pragma unroll
  for (int it = 0; it < 16; ++it) {
    int e = base + it * 1024 + threadIdx.x;
    if (e < E) {
      unsigned b = bb[it];
      ep[lbase[b] + rank[it]] =
          (((unsigned)src[e]) << BSH) | (((unsigned)dst[e]) & BMASK);
    }
  }
}

// ------------------------- phase 2: in-bucket sort -------------------------
__global__ __launch_bounds__(256) void bsort_k(const unsigned* __restrict__ ep,
                                               const unsigned* __restrict__ boff,
                                               int* __restrict__ ssrc,
                                               unsigned* __restrict__ rows) {
  __shared__ unsigned cnt[128];
  __shared__ unsigned sc[128];
  const int tid = threadIdx.x;
  const unsigned beg = boff[blockIdx.x], end = boff[blockIdx.x + 1];
  if (tid < 128) cnt[tid] = 0;
  __syncthreads();
  for (unsigned j = beg + tid; j < end; j += 256)
    atomicAdd(&cnt[ep[j] & BMASK], 1u);
  __syncthreads();
  unsigned v = (tid < 128) ? cnt[tid] : 0u;
  if (tid < 128) sc[tid] = v;
  __syncthreads();
  for (int off = 1; off < 128; off <<= 1) {
    unsigned t = (tid < 128 && tid >= off) ? sc[tid - off] : 0u;
    __syncthreads();
    if (tid < 128) sc[tid] += t;
    __syncthreads();
  }
  unsigned ex = sc[tid] - v;
  if (tid < 128) {
    rows[blockIdx.x * 128 + tid] = beg + ex;
    cnt[tid] = ex;
  }
  __syncthreads();
  for (unsigned j = beg + tid; j < end; j += 256) {
    unsigned p = ep[j];
    unsigned r = atomicAdd(&cnt[p & BMASK], 1u);
    ssrc[beg + r] = (int)(p >> BSH);
  }
}

// ---------------------------------------------------------------------------
// bf16 gather-mean with fused epilogue:
//   out[node][:] = act( mean_j valb[ssrc[j]][:] + base[node][:] )
// valb rows are F bf16 (F/2 uints). P = F/2 lanes per node, each lane owns a
// bf16 pair -> uint loads. 8 clamped loads in flight (latency-bound, deg~16).
// ---------------------------------------------------------------------------
template <int LOGF, bool RELU>
__global__ __launch_bounds__(256) void gatherb_k(
    const unsigned* __restrict__ valb, const int* __restrict__ ssrc,
    const unsigned* __restrict__ rows, const float* __restrict__ base,
    float* __restrict__ out, int N) {
  constexpr int P = 1 << (LOGF - 1);  // uints per row: 32 (F=64) / 16 (F=32)
  const int node = blockIdx.x * (256 / P) + threadIdx.x / P;
  const int p = threadIdx.x & (P - 1);
  if (node >= N) return;
  const unsigned beg = rows[node], end = rows[node + 1];
  float ax = 0.f, ay = 0.f;
  if (end > beg) {
    const unsigned last = end - 1;
    for (unsigned j = beg; j < end; j += 8) {
      float sx = 0.f, sy = 0.f;
#pragma unroll
      for (int i = 0; i < 8; ++i) {
        unsigned jj = j + i;
        unsigned idx = jj < last ? jj : last;  // clamp: load always issued
        int sn = ssrc[idx];
        unsigned u = valb[(size_t)sn * P + p];
        bool ok = jj < end;
        sx += ok ? bflo(u) : 0.f;
        sy += ok ? bfhi(u) : 0.f;
      }
      ax += sx;
      ay += sy;
    }
  }
  const unsigned dg = end - beg;
  const float inv = dg ? 1.f / (float)dg : 0.f;
  const size_t o = (size_t)node * (2 * P) + 2 * p;
  float vx = ax * inv + base[o];
  float vy = ay * inv + base[o + 1];
  if (RELU) {
    vx = fmaxf(vx, 0.f);
    vy = fmaxf(vy, 0.f);
  }
  float2 ov = {vx, vy};
  *(float2*)&out[o] = ov;
}

extern "C" void kernel_launch(void* const* d_in, const int* in_sizes, int n_in,
                              void* d_out, int out_size, void* d_ws,
                              size_t ws_size, hipStream_t stream) {
  const float* x   = (const float*)d_in[0];
  const int*   ei  = (const int*)d_in[1];  // [2, E]: row0 = src, row1 = dst
  const float* W1n = (const float*)d_in[2];
  const float* W1s = (const float*)d_in[3];
  const float* b1  = (const float*)d_in[4];
  const float* W2n = (const float*)d_in[5];
  const float* W2s = (const float*)d_in[6];
  const float* b2  = (const float*)d_in[7];
  float* out = (float*)d_out;

  const int E = in_sizes[1] / 2;  // 1,600,000
  const int M = N_NODES;
  const int* src = ei;
  const int* dst = ei + E;

  // Workspace layout (bytes):
  //   ep    @ 0           6,400,000
  //   ssrc  @ 6,400,000   6,400,000
  //   rows  @ 12,800,000    401,412
  //   bcnt  @ 13,203,456      3,136
  //   boff  @ 13,207,552      3,140
  //   bcur  @ 13,211,648      3,136
  //   xnb   @ 13,215,744 12,800,000  (bf16 M x 64; layer2: hnb bf16 M x 32)
  //   xs    @ 26,015,744 25,600,000  (f32 M x 64;  layer2: hs f32 M x 32)
  //   h     @ 51,615,744 25,600,000  (f32 M x 64)
  char* wsb = (char*)d_ws;
  unsigned*       ep   = (unsigned*)(wsb);
  int*            ssrc = (int*)(wsb + 6400000);
  unsigned*       rows = (unsigned*)(wsb + 12800000);
  unsigned*       bcnt = (unsigned*)(wsb + 13203456);
  unsigned*       boff = (unsigned*)(wsb + 13207552);
  unsigned*       bcur = (unsigned*)(wsb + 13211648);
  unsigned short* xnb  = (unsigned short*)(wsb + 13215744);
  float*          xs   = (float*)(wsb + 26015744);
  float*          h    = (float*)(wsb + 51615744);
  unsigned short* hnb  = xnb;  // layer-2 reuse
  float*          hs   = xs;   // layer-2 reuse

  const int EB = (E + 16383) / 16384;  // 98

  // ---- dst-sorted edge list (CSR), block-private writes only ----
  hipMemsetAsync(bcnt, 0, NB * 4, stream);
  bhist_k<<<EB, 1024, 0, stream>>>(dst, bcnt, E);
  bscan_k<<<1, 1024, 0, stream>>>(bcnt, boff, bcur);
  bscatter_k<<<EB, 1024, 0, stream>>>(src, dst, bcur, ep, E);
  bsort_k<<<NB, 256, 0, stream>>>(ep, boff, ssrc, rows);

  // ---- Layer 1: xn(bf16)/xs = x@{W1n,W1s}+b1 ; h = relu(mean(xn[src]) + xs)
  gemm1_k<<<(M + 63) / 64, 256, 0, stream>>>(x, W1n, W1s, b1, xnb, xs, M);
  gatherb_k<6, true><<<M / 8, 256, 0, stream>>>((const unsigned*)xnb, ssrc,
                                                rows, xs, h, M);

  // ---- Layer 2: hn(bf16)/hs = h@{W2n,W2s}+b2 ; out = mean(hn[src]) + hs ----
  gemm2_k<<<(M + 127) / 128, 256, 0, stream>>>(h, W2n, W2s, b2, hnb, hs, M);
  gatherb_k<5, false><<<M / 16, 256, 0, stream>>>((const unsigned*)hnb, ssrc,
                                                  rows, hs, out, M);
}

// Round 9
// 233.483 us; speedup vs baseline: 5.5741x; 1.0112x over previous
//
#include <hip/hip_runtime.h>
#include <hip/hip_bf16.h>

#define N_NODES 100000
#define NB 784   // buckets of 128 nodes: 784*128 = 100352 >= N_NODES
#define NPAD 100352
#define BSH 7
#define BMASK 127
#define APAD 68  // padded LDS row stride (floats)

__device__ inline void fma4(float a, const float4& w, float4& c) {
  c.x = fmaf(a, w.x, c.x);
  c.y = fmaf(a, w.y, c.y);
  c.z = fmaf(a, w.z, c.z);
  c.w = fmaf(a, w.w, c.w);
}
__device__ inline unsigned short f2bf(float f) {  // RNE f32->bf16
  unsigned u = __float_as_uint(f);
  u += 0x7fffu + ((u >> 16) & 1u);
  return (unsigned short)(u >> 16);
}
__device__ inline float bflo(unsigned u) { return __uint_as_float(u << 16); }
__device__ inline float bfhi(unsigned u) { return __uint_as_float(u & 0xffff0000u); }

// ---------------------------------------------------------------------------
// Layer-1 dual-GEMM over x:  xn = x@W1n (bf16 out),  xs = x@W1s + b1 (f32).
// Block tile 64r x 64c, thread tile 4x4x2; A staged in LDS (R7-proven shape).
// ---------------------------------------------------------------------------
__global__ __launch_bounds__(256) void gemm1_k(
    const float* __restrict__ x, const float* __restrict__ W1n,
    const float* __restrict__ W1s, const float* __restrict__ b1,
    unsigned short* __restrict__ xnb, float* __restrict__ xs, int M) {
  __shared__ float Wn[64 * 64];
  __shared__ float Ws[64 * 64];
  __shared__ float Ax[64 * APAD];
  const int tid = threadIdx.x;
  const int row0 = blockIdx.x * 64;

  for (int i = tid; i < 1024; i += 256) {
    ((float4*)Wn)[i] = ((const float4*)W1n)[i];
    ((float4*)Ws)[i] = ((const float4*)W1s)[i];
  }
  for (int i = tid; i < 1024; i += 256) {
    int r = i >> 4, c = i & 15;
    long long gr = row0 + r;
    if (gr >= M) gr = M - 1;
    float4 v = ((const float4*)(x + gr * 64))[c];
    *(float4*)&Ax[r * APAD + 4 * c] = v;
  }
  __syncthreads();

  const int tx = tid & 15;
  const int ty = tid >> 4;
  const int arow = ty * 4;

  float4 an[4], as[4];
#pragma unroll
  for (int r = 0; r < 4; ++r) {
    an[r] = make_float4(0.f, 0.f, 0.f, 0.f);
    as[r] = make_float4(0.f, 0.f, 0.f, 0.f);
  }

#pragma unroll 1
  for (int k4 = 0; k4 < 16; ++k4) {
    float4 wn0 = *(const float4*)&Wn[(4 * k4 + 0) * 64 + 4 * tx];
    float4 wn1 = *(const float4*)&Wn[(4 * k4 + 1) * 64 + 4 * tx];
    float4 wn2 = *(const float4*)&Wn[(4 * k4 + 2) * 64 + 4 * tx];
    float4 wn3 = *(const float4*)&Wn[(4 * k4 + 3) * 64 + 4 * tx];
    float4 ws0 = *(const float4*)&Ws[(4 * k4 + 0) * 64 + 4 * tx];
    float4 ws1 = *(const float4*)&Ws[(4 * k4 + 1) * 64 + 4 * tx];
    float4 ws2 = *(const float4*)&Ws[(4 * k4 + 2) * 64 + 4 * tx];
    float4 ws3 = *(const float4*)&Ws[(4 * k4 + 3) * 64 + 4 * tx];
#pragma unroll
    for (int r = 0; r < 4; ++r) {
      float4 a = *(const float4*)&Ax[(arow + r) * APAD + 4 * k4];
      fma4(a.x, wn0, an[r]);
      fma4(a.y, wn1, an[r]);
      fma4(a.z, wn2, an[r]);
      fma4(a.w, wn3, an[r]);
      fma4(a.x, ws0, as[r]);
      fma4(a.y, ws1, as[r]);
      fma4(a.z, ws2, as[r]);
      fma4(a.w, ws3, as[r]);
    }
  }

  const float4 bv = *(const float4*)&b1[4 * tx];
#pragma unroll
  for (int r = 0; r < 4; ++r) {
    int row = row0 + arow + r;
    if (row < M) {
      float4 o;
      o.x = as[r].x + bv.x;
      o.y = as[r].y + bv.y;
      o.z = as[r].z + bv.z;
      o.w = as[r].w + bv.w;
      *(float4*)&xs[(long long)row * 64 + 4 * tx] = o;
      ushort4 p;
      p.x = f2bf(an[r].x);
      p.y = f2bf(an[r].y);
      p.z = f2bf(an[r].z);
      p.w = f2bf(an[r].w);
      *(ushort4*)&xnb[(long long)row * 64 + 4 * tx] = p;
    }
  }
}

// ---------------------------------------------------------------------------
// Layer-2 dual-GEMM over h: hn = h@W2n (bf16 out), hs = h@W2s + b2 (f32).
// Block tile 128r x 32c, thread tile 4x4x2; h staged in LDS.
// ---------------------------------------------------------------------------
__global__ __launch_bounds__(256) void gemm2_k(
    const float* __restrict__ h, const float* __restrict__ W2n,
    const float* __restrict__ W2s, const float* __restrict__ b2,
    unsigned short* __restrict__ hnb, float* __restrict__ hs, int M) {
  __shared__ float Wn[64 * 32];
  __shared__ float Ws[64 * 32];
  __shared__ float Ah[128 * APAD];
  const int tid = threadIdx.x;
  const int row0 = blockIdx.x * 128;

  for (int i = tid; i < 512; i += 256) {
    ((float4*)Wn)[i] = ((const float4*)W2n)[i];
    ((float4*)Ws)[i] = ((const float4*)W2s)[i];
  }
  for (int i = tid; i < 2048; i += 256) {
    int r = i >> 4, c = i & 15;
    long long gr = row0 + r;
    if (gr >= M) gr = M - 1;
    float4 v = ((const float4*)(h + gr * 64))[c];
    *(float4*)&Ah[r * APAD + 4 * c] = v;
  }
  __syncthreads();

  const int tx = tid & 7;
  const int ty = tid >> 3;
  const int arow = ty * 4;

  float4 an[4], as[4];
#pragma unroll
  for (int r = 0; r < 4; ++r) {
    an[r] = make_float4(0.f, 0.f, 0.f, 0.f);
    as[r] = make_float4(0.f, 0.f, 0.f, 0.f);
  }

#pragma unroll 1
  for (int k4 = 0; k4 < 16; ++k4) {
    float4 wn0 = *(const float4*)&Wn[(4 * k4 + 0) * 32 + 4 * tx];
    float4 wn1 = *(const float4*)&Wn[(4 * k4 + 1) * 32 + 4 * tx];
    float4 wn2 = *(const float4*)&Wn[(4 * k4 + 2) * 32 + 4 * tx];
    float4 wn3 = *(const float4*)&Wn[(4 * k4 + 3) * 32 + 4 * tx];
    float4 ws0 = *(const float4*)&Ws[(4 * k4 + 0) * 32 + 4 * tx];
    float4 ws1 = *(const float4*)&Ws[(4 * k4 + 1) * 32 + 4 * tx];
    float4 ws2 = *(const float4*)&Ws[(4 * k4 + 2) * 32 + 4 * tx];
    float4 ws3 = *(const float4*)&Ws[(4 * k4 + 3) * 32 + 4 * tx];
#pragma unroll
    for (int r = 0; r < 4; ++r) {
      float4 a = *(const float4*)&Ah[(arow + r) * APAD + 4 * k4];
      fma4(a.x, wn0, an[r]);
      fma4(a.y, wn1, an[r]);
      fma4(a.z, wn2, an[r]);
      fma4(a.w, wn3, an[r]);
      fma4(a.x, ws0, as[r]);
      fma4(a.y, ws1, as[r]);
      fma4(a.z, ws2, as[r]);
      fma4(a.w, ws3, as[r]);
    }
  }

  const float4 bv = *(const float4*)&b2[4 * tx];
#pragma unroll
  for (int r = 0; r < 4; ++r) {
    int row = row0 + arow + r;
    if (row < M) {
      float4 o;
      o.x = as[r].x + bv.x;
      o.y = as[r].y + bv.y;
      o.z = as[r].z + bv.z;
      o.w = as[r].w + bv.w;
      *(float4*)&hs[(long long)row * 32 + 4 * tx] = o;
      ushort4 p;
      p.x = f2bf(an[r].x);
      p.y = f2bf(an[r].y);
      p.z = f2bf(an[r].z);
      p.w = f2bf(an[r].w);
      *(ushort4*)&hnb[(long long)row * 32 + 4 * tx] = p;
    }
  }
}

// ------------------------- phase 1: coarse buckets -------------------------
__global__ __launch_bounds__(1024) void bhist_k(const int* __restrict__ dst,
                                                unsigned* __restrict__ bcnt,
                                                int E) {
  __shared__ unsigned lh[NB];
  for (int i = threadIdx.x; i < NB; i += 1024) lh[i] = 0;
  __syncthreads();
  const int base = blockIdx.x * 16384;
#pragma unroll
  for (int it = 0; it < 16; ++it) {
    int e = base + it * 1024 + threadIdx.x;
    if (e < E) atomicAdd(&lh[((unsigned)dst[e]) >> BSH], 1u);
  }
  __syncthreads();
  for (int i = threadIdx.x; i < NB; i += 1024)
    if (lh[i]) atomicAdd(&bcnt[i], lh[i]);
}

__global__ __launch_bounds__(1024) void bscan_k(const unsigned* __restrict__ bcnt,
                                                unsigned* __restrict__ boff,
                                                unsigned* __restrict__ bcur) {
  __shared__ unsigned s[1024];
  const int tid = threadIdx.x;
  unsigned v = (tid < NB) ? bcnt[tid] : 0u;
  s[tid] = v;
  __syncthreads();
  for (int off = 1; off < 1024; off <<= 1) {
    unsigned t = (tid >= off) ? s[tid - off] : 0u;
    __syncthreads();
    s[tid] += t;
    __syncthreads();
  }
  unsigned ex = s[tid] - v;
  if (tid < NB) {
    boff[tid] = ex;
    bcur[tid] = ex;
  }
  if (tid == NB - 1) boff[NB] = ex + v;
}

__global__ __launch_bounds__(1024) void bscatter_k(const int* __restrict__ src,
                                                   const int* __restrict__ dst,
                                                   unsigned* __restrict__ bcur,
                                                   unsigned* __restrict__ ep,
                                                   int E) {
  __shared__ unsigned lh[NB];
  __shared__ unsigned lbase[NB];
  for (int i = threadIdx.x; i < NB; i += 1024) lh[i] = 0;
  __syncthreads();
  const int base = blockIdx.x * 16384;
  unsigned short rank[16];
  unsigned short bb[16];
#pragma unroll
  for (int it = 0; it < 16; ++it) {
    int e = base + it * 1024 + threadIdx.x;
    if (e < E) {
      unsigned b = ((unsigned)dst[e]) >> BSH;
      bb[it] = (unsigned short)b;
      rank[it] = (unsigned short)atomicAdd(&lh[b], 1u);
    }
  }
  __syncthreads();
  for (int i = threadIdx.x; i < NB; i += 1024)
    lbase[i] = lh[i] ? atomicAdd(&bcur[i], lh[i]) : 0u;
  __syncthreads();
#pragma unroll
  for (int it = 0; it < 16; ++it) {
    int e = base + it * 1024 + threadIdx.x;
    if (e < E) {
      unsigned b = bb[it];
      ep[lbase[b] + rank[it]] =
          (((unsigned)src[e]) << BSH) | (((unsigned)dst[e]) & BMASK);
    }
  }
}

// ------------------------- phase 2: in-bucket sort -------------------------
__global__ __launch_bounds__(256) void bsort_k(const unsigned* __restrict__ ep,
                                               const unsigned* __restrict__ boff,
                                               int* __restrict__ ssrc,
                                               unsigned* __restrict__ rows) {
  __shared__ unsigned cnt[128];
  __shared__ unsigned sc[128];
  const int tid = threadIdx.x;
  const unsigned beg = boff[blockIdx.x], end = boff[blockIdx.x + 1];
  if (tid < 128) cnt[tid] = 0;
  __syncthreads();
  for (unsigned j = beg + tid; j < end; j += 256)
    atomicAdd(&cnt[ep[j] & BMASK], 1u);
  __syncthreads();
  unsigned v = (tid < 128) ? cnt[tid] : 0u;
  if (tid < 128) sc[tid] = v;
  __syncthreads();
  for (int off = 1; off < 128; off <<= 1) {
    unsigned t = (tid < 128 && tid >= off) ? sc[tid - off] : 0u;
    __syncthreads();
    if (tid < 128) sc[tid] += t;
    __syncthreads();
  }
  unsigned ex = sc[tid] - v;
  if (tid < 128) {
    rows[blockIdx.x * 128 + tid] = beg + ex;
    cnt[tid] = ex;
  }
  __syncthreads();
  for (unsigned j = beg + tid; j < end; j += 256) {
    unsigned p = ep[j];
    unsigned r = atomicAdd(&cnt[p & BMASK], 1u);
    ssrc[beg + r] = (int)(p >> BSH);
  }
}

// ---------------------------------------------------------------------------
// bf16 gather-mean, uint4 (8 bf16 = 16B) per lane, P = F/8 lanes per node:
//   out[node][:] = act( mean_j valb[ssrc[j]][:] + base[node][:] )
// Bulk loop: unpredicated groups of 8 edges (8 x 16B loads in flight/lane);
// tail: one clamped+predicated group. VALU/byte ~2.3x lower than uint/lane.
// ---------------------------------------------------------------------------
template <int LOGF, bool RELU>
__global__ __launch_bounds__(256) void gatherb_k(
    const uint4* __restrict__ valb4, const int* __restrict__ ssrc,
    const unsigned* __restrict__ rows, const float* __restrict__ base,
    float* __restrict__ out, int N) {
  constexpr int P = (1 << LOGF) / 8;  // uint4s per row: 8 (F=64) / 4 (F=32)
  const int node = blockIdx.x * (256 / P) + threadIdx.x / P;
  const int p = threadIdx.x & (P - 1);
  if (node >= N) return;
  const unsigned beg = rows[node], end = rows[node + 1];

  float acc[8];
#pragma unroll
  for (int q = 0; q < 8; ++q) acc[q] = 0.f;

  unsigned j = beg;
  // bulk: full groups of 8, no predication
  for (; j + 8 <= end; j += 8) {
    int sn[8];
#pragma unroll
    for (int i = 0; i < 8; ++i) sn[i] = ssrc[j + i];
    uint4 u[8];
#pragma unroll
    for (int i = 0; i < 8; ++i) u[i] = valb4[(size_t)sn[i] * P + p];
#pragma unroll
    for (int i = 0; i < 8; ++i) {
      acc[0] += bflo(u[i].x);
      acc[1] += bfhi(u[i].x);
      acc[2] += bflo(u[i].y);
      acc[3] += bfhi(u[i].y);
      acc[4] += bflo(u[i].z);
      acc[5] += bfhi(u[i].z);
      acc[6] += bflo(u[i].w);
      acc[7] += bfhi(u[i].w);
    }
  }
  // tail: one clamped + predicated group (loads always issued -> stay in flight)
  if (j < end) {
    const unsigned last = end - 1;
    int sn[8];
#pragma unroll
    for (int i = 0; i < 8; ++i) {
      unsigned jj = j + i;
      sn[i] = ssrc[jj < last ? jj : last];
    }
    uint4 u[8];
#pragma unroll
    for (int i = 0; i < 8; ++i) u[i] = valb4[(size_t)sn[i] * P + p];
#pragma unroll
    for (int i = 0; i < 8; ++i) {
      bool ok = (j + i) < end;
      acc[0] += ok ? bflo(u[i].x) : 0.f;
      acc[1] += ok ? bfhi(u[i].x) : 0.f;
      acc[2] += ok ? bflo(u[i].y) : 0.f;
      acc[3] += ok ? bfhi(u[i].y) : 0.f;
      acc[4] += ok ? bflo(u[i].z) : 0.f;
      acc[5] += ok ? bfhi(u[i].z) : 0.f;
      acc[6] += ok ? bflo(u[i].w) : 0.f;
      acc[7] += ok ? bfhi(u[i].w) : 0.f;
    }
  }

  const unsigned dg = end - beg;
  const float inv = dg ? 1.f / (float)dg : 0.f;
  const size_t o = (size_t)node * (8 * P) + 8 * p;
  float4 b0 = *(const float4*)&base[o];
  float4 b1 = *(const float4*)&base[o + 4];
  float4 o0, o1;
  o0.x = acc[0] * inv + b0.x;
  o0.y = acc[1] * inv + b0.y;
  o0.z = acc[2] * inv + b0.z;
  o0.w = acc[3] * inv + b0.w;
  o1.x = acc[4] * inv + b1.x;
  o1.y = acc[5] * inv + b1.y;
  o1.z = acc[6] * inv + b1.z;
  o1.w = acc[7] * inv + b1.w;
  if (RELU) {
    o0.x = fmaxf(o0.x, 0.f);
    o0.y = fmaxf(o0.y, 0.f);
    o0.z = fmaxf(o0.z, 0.f);
    o0.w = fmaxf(o0.w, 0.f);
    o1.x = fmaxf(o1.x, 0.f);
    o1.y = fmaxf(o1.y, 0.f);
    o1.z = fmaxf(o1.z, 0.f);
    o1.w = fmaxf(o1.w, 0.f);
  }
  *(float4*)&out[o] = o0;
  *(float4*)&out[o + 4] = o1;
}

extern "C" void kernel_launch(void* const* d_in, const int* in_sizes, int n_in,
                              void* d_out, int out_size, void* d_ws,
                              size_t ws_size, hipStream_t stream) {
  const float* x   = (const float*)d_in[0];
  const int*   ei  = (const int*)d_in[1];  // [2, E]: row0 = src, row1 = dst
  const float* W1n = (const float*)d_in[2];
  const float* W1s = (const float*)d_in[3];
  const float* b1  = (const float*)d_in[4];
  const float* W2n = (const float*)d_in[5];
  const float* W2s = (const float*)d_in[6];
  const float* b2  = (const float*)d_in[7];
  float* out = (float*)d_out;

  const int E = in_sizes[1] / 2;  // 1,600,000
  const int M = N_NODES;
  const int* src = ei;
  const int* dst = ei + E;

  // Workspace layout (bytes):
  //   ep    @ 0           6,400,000
  //   ssrc  @ 6,400,000   6,400,000
  //   rows  @ 12,800,000    401,412
  //   bcnt  @ 13,203,456      3,136
  //   boff  @ 13,207,552      3,140
  //   bcur  @ 13,211,648      3,136
  //   xnb   @ 13,215,744 12,800,000  (bf16 M x 64; layer2: hnb bf16 M x 32)
  //   xs    @ 26,015,744 25,600,000  (f32 M x 64;  layer2: hs f32 M x 32)
  //   h     @ 51,615,744 25,600,000  (f32 M x 64)
  char* wsb = (char*)d_ws;
  unsigned*       ep   = (unsigned*)(wsb);
  int*            ssrc = (int*)(wsb + 6400000);
  unsigned*       rows = (unsigned*)(wsb + 12800000);
  unsigned*       bcnt = (unsigned*)(wsb + 13203456);
  unsigned*       boff = (unsigned*)(wsb + 13207552);
  unsigned*       bcur = (unsigned*)(wsb + 13211648);
  unsigned short* xnb  = (unsigned short*)(wsb + 13215744);
  float*          xs   = (float*)(wsb + 26015744);
  float*          h    = (float*)(wsb + 51615744);
  unsigned short* hnb  = xnb;  // layer-2 reuse
  float*          hs   = xs;   // layer-2 reuse

  const int EB = (E + 16383) / 16384;  // 98

  // ---- dst-sorted edge list (CSR), block-private writes only ----
  hipMemsetAsync(bcnt, 0, NB * 4, stream);
  bhist_k<<<EB, 1024, 0, stream>>>(dst, bcnt, E);
  bscan_k<<<1, 1024, 0, stream>>>(bcnt, boff, bcur);
  bscatter_k<<<EB, 1024, 0, stream>>>(src, dst, bcur, ep, E);
  bsort_k<<<NB, 256, 0, stream>>>(ep, boff, ssrc, rows);

  // ---- Layer 1: xn(bf16)/xs = x@{W1n,W1s}+b1 ; h = relu(mean(xn[src]) + xs)
  gemm1_k<<<(M + 63) / 64, 256, 0, stream>>>(x, W1n, W1s, b1, xnb, xs, M);
  gatherb_k<6, true><<<(M + 31) / 32, 256, 0, stream>>>(
      (const uint4*)xnb, ssrc, rows, xs, h, M);

  // ---- Layer 2: hn(bf16)/hs = h@{W2n,W2s}+b2 ; out = mean(hn[src]) + hs ----
  gemm2_k<<<(M + 127) / 128, 256, 0, stream>>>(h, W2n, W2s, b2, hnb, hs, M);
  gatherb_k<5, false><<<(M + 63) / 64, 256, 0, stream>>>(
      (const uint4*)hnb, ssrc, rows, hs, out, M);
}